// Round 1
// baseline (268.651 us; speedup 1.0000x reference)
//
#include <hip/hip_runtime.h>

#define BS 1024
#define D 128
#define NC 100000
#define S_SCALE 30.0f
#define MARGIN 0.35f
#define NTILES 782   /* ceil(100000/128) */
#define GRIDY 98

typedef __attribute__((ext_vector_type(8))) short bf16x8;
typedef __attribute__((ext_vector_type(4))) float f32x4;

__device__ __forceinline__ unsigned short f2bf(float f) {
    union { float f; unsigned u; } x; x.f = f;
    unsigned u = x.u;
    u += 0x7FFFu + ((u >> 16) & 1u);   // round-to-nearest-even
    return (unsigned short)(u >> 16);
}

// One wave per input row: l2-normalize, emit f32 + bf16, count labels.
__global__ void prep_fn(const float* __restrict__ inp, const int* __restrict__ label,
                        float* __restrict__ fn_f32, unsigned short* __restrict__ fn_bf16,
                        float* __restrict__ counts) {
    int row = blockIdx.x;
    int lane = threadIdx.x;  // blockDim = 64
    float2 v = *(const float2*)(inp + row * D + lane * 2);
    float s = v.x * v.x + v.y * v.y;
    #pragma unroll
    for (int m = 1; m < 64; m <<= 1) s += __shfl_xor(s, m);
    float inv = 1.0f / fmaxf(sqrtf(s), 1e-12f);
    float a = v.x * inv, b = v.y * inv;
    *(float2*)(fn_f32 + row * D + lane * 2) = make_float2(a, b);
    unsigned pack = (unsigned)f2bf(a) | ((unsigned)f2bf(b) << 16);
    ((unsigned*)fn_bf16)[row * 64 + lane] = pack;
    if (lane == 0) atomicAdd(counts + label[row], 1.0f);
}

// 4 waves/block, one weight row per wave: l2-normalize -> bf16.
__global__ void prep_wn(const float* __restrict__ wt, unsigned short* __restrict__ wn_bf16) {
    int wv = threadIdx.x >> 6, lane = threadIdx.x & 63;
    int row = blockIdx.x * 4 + wv;      // grid 25000 -> exactly 100000
    float2 v = *(const float2*)(wt + row * D + lane * 2);
    float s = v.x * v.x + v.y * v.y;
    #pragma unroll
    for (int m = 1; m < 64; m <<= 1) s += __shfl_xor(s, m);
    float inv = 1.0f / fmaxf(sqrtf(s), 1e-12f);
    unsigned pack = (unsigned)f2bf(v.x * inv) | ((unsigned)f2bf(v.y * inv) << 16);
    ((unsigned*)wn_bf16)[row * 64 + lane] = pack;
}

// Main fused GEMM + exp-accumulate. Block = 256 thr (4 waves, 2x2 over 128x128 tile).
// LDS granule swizzle: slot(row,kb) = row*16 + (kb ^ (row&15)), 16B granules ->
// 2-way-max bank aliasing on ds_read_b128 (free per m136).
__global__ __launch_bounds__(256, 2) void main_gemm(
    const unsigned short* __restrict__ fnb, const unsigned short* __restrict__ wnb,
    const int* __restrict__ label, float* __restrict__ sumexp, float* __restrict__ pos) {
    __shared__ __align__(16) short As[128 * 128];  // 32 KB
    __shared__ __align__(16) short Bs[128 * 128];  // 32 KB
    int tid = threadIdx.x;
    int lane = tid & 63, w = tid >> 6;
    int quad = lane >> 4, l15 = lane & 15;
    int m0 = (w >> 1) * 64, n0 = (w & 1) * 64;
    int rowbase = blockIdx.x * 128;   // 8 row tiles cover 1024 rows

    // Stage A once (row tile fixed for the whole block).
    #pragma unroll
    for (int i = 0; i < 8; i++) {
        int g = i * 256 + tid;
        int row = g >> 4, kb = g & 15;
        uint4 v = *(const uint4*)(fnb + ((rowbase + row) * D + kb * 8));
        *(uint4*)(As + (row * 16 + (kb ^ (row & 15))) * 8) = v;
    }

    // Labels for the 16 rows this lane's accumulators touch.
    int lab[16];
    #pragma unroll
    for (int mt = 0; mt < 4; mt++)
        #pragma unroll
        for (int r = 0; r < 4; r++)
            lab[mt * 4 + r] = label[rowbase + m0 + mt * 16 + quad * 4 + r];

    float sums[16];
    #pragma unroll
    for (int i = 0; i < 16; i++) sums[i] = 0.0f;

    for (int tile = blockIdx.y; tile < NTILES; tile += GRIDY) {
        int ct = tile * 128;
        uint4 breg[8];
        #pragma unroll
        for (int i = 0; i < 8; i++) {
            int g = i * 256 + tid;
            int row = g >> 4, kb = g & 15;
            int cls = ct + row; if (cls > NC - 1) cls = NC - 1;  // clamp; masked in epilogue
            breg[i] = *(const uint4*)(wnb + (cls * D + kb * 8));
        }
        __syncthreads();   // previous tile's LDS reads done (covers A stores on iter 0)
        #pragma unroll
        for (int i = 0; i < 8; i++) {
            int g = i * 256 + tid;
            int row = g >> 4, kb = g & 15;
            *(uint4*)(Bs + (row * 16 + (kb ^ (row & 15))) * 8) = breg[i];
        }
        __syncthreads();

        f32x4 acc[4][4];
        #pragma unroll
        for (int mt = 0; mt < 4; mt++)
            #pragma unroll
            for (int nt = 0; nt < 4; nt++)
                acc[mt][nt] = (f32x4){0.0f, 0.0f, 0.0f, 0.0f};

        #pragma unroll
        for (int ks = 0; ks < 4; ks++) {
            int kb = ks * 4 + quad;
            bf16x8 af[4], bf[4];
            #pragma unroll
            for (int mt = 0; mt < 4; mt++) {
                int row = m0 + mt * 16 + l15;          // row&15 == l15
                af[mt] = *(const bf16x8*)(As + (row * 16 + (kb ^ l15)) * 8);
            }
            #pragma unroll
            for (int nt = 0; nt < 4; nt++) {
                int row = n0 + nt * 16 + l15;
                bf[nt] = *(const bf16x8*)(Bs + (row * 16 + (kb ^ l15)) * 8);
            }
            #pragma unroll
            for (int mt = 0; mt < 4; mt++)
                #pragma unroll
                for (int nt = 0; nt < 4; nt++)
                    acc[mt][nt] = __builtin_amdgcn_mfma_f32_16x16x32_bf16(
                        af[mt], bf[nt], acc[mt][nt], 0, 0, 0);
        }

        // Epilogue: C/D layout col=lane&15, row=quad*4+reg (m89-verified).
        #pragma unroll
        for (int nt = 0; nt < 4; nt++) {
            int col = ct + n0 + nt * 16 + l15;
            bool cv = col < NC;
            #pragma unroll
            for (int mt = 0; mt < 4; mt++) {
                #pragma unroll
                for (int r = 0; r < 4; r++) {
                    float logit = S_SCALE * acc[mt][nt][r];
                    float e = __expf(logit - 30.0f);   // safe fixed shift: logit <= 30
                    if (cv) {
                        if (col == lab[mt * 4 + r]) {
                            pos[rowbase + m0 + mt * 16 + quad * 4 + r] = logit;  // unique writer
                        } else {
                            sums[mt * 4 + r] += e;
                        }
                    }
                }
            }
        }
    }

    // Reduce partial sums across the 16 lanes of each quad, then one atomic per row.
    #pragma unroll
    for (int mt = 0; mt < 4; mt++) {
        #pragma unroll
        for (int r = 0; r < 4; r++) {
            float s = sums[mt * 4 + r];
            s += __shfl_xor(s, 1);
            s += __shfl_xor(s, 2);
            s += __shfl_xor(s, 4);
            s += __shfl_xor(s, 8);
            if (l15 == 0)
                atomicAdd(sumexp + rowbase + m0 + mt * 16 + quad * 4 + r, s);
        }
    }
}

// loss = mean softplus(M + 30 + log(sumexp) - pos)
__global__ void loss_k(const float* __restrict__ sumexp, const float* __restrict__ pos,
                       float* __restrict__ out) {
    __shared__ float red[256];
    int t = threadIdx.x;
    float acc = 0.0f;
    #pragma unroll
    for (int i = 0; i < 4; i++) {
        int r = t + i * 256;
        float lse = 30.0f + logf(sumexp[r]);
        float z = MARGIN + lse - pos[r];
        acc += fmaxf(z, 0.0f) + log1pf(__expf(-fabsf(z)));
    }
    red[t] = acc;
    __syncthreads();
    for (int s = 128; s > 0; s >>= 1) {
        if (t < s) red[t] += red[t + s];
        __syncthreads();
    }
    if (t == 0) out[0] = red[0] * (1.0f / 1024.0f);
}

// Weight output: present classes -> 0 (filled by addmean), absent -> copy.
__global__ void wout_k(const float* __restrict__ wt, const float* __restrict__ counts,
                       float* __restrict__ outw) {
    int idx = blockIdx.x * 256 + threadIdx.x;  // grid 50000 -> 12.8M elements
    int row = idx >> 7;
    float c = counts[row];
    outw[idx] = (c > 0.0f) ? 0.0f : wt[idx];
}

__global__ void addmean_k(const float* __restrict__ fn_f32, const int* __restrict__ label,
                          const float* __restrict__ counts, float* __restrict__ outw) {
    int b = blockIdx.x, t = threadIdx.x;  // 1024 x 128
    int c = label[b];
    float cnt = counts[c];
    atomicAdd(outw + c * D + t, fn_f32[b * D + t] / cnt);
}

extern "C" void kernel_launch(void* const* d_in, const int* in_sizes, int n_in,
                              void* d_out, int out_size, void* d_ws, size_t ws_size,
                              hipStream_t stream) {
    (void)in_sizes; (void)n_in; (void)out_size; (void)ws_size;
    const float* inp   = (const float*)d_in[0];
    const int*   label = (const int*)d_in[1];
    const float* wt    = (const float*)d_in[2];
    float* out = (float*)d_out;

    char* w = (char*)d_ws;
    float*          fn_f32  = (float*)(w);                    // 524288 B
    unsigned short* fn_bf16 = (unsigned short*)(w + 524288);  // 262144 B
    unsigned short* wn_bf16 = (unsigned short*)(w + 786432);  // 25600000 B
    float*          sumexp  = (float*)(w + 26386432);         // 4096 B
    float*          pos     = (float*)(w + 26390528);         // 4096 B
    float*          counts  = (float*)(w + 26394624);         // 400000 B

    // zero sumexp + pos + counts (contiguous)
    hipMemsetAsync(w + 26386432, 0, 408192, stream);

    prep_fn<<<BS, 64, 0, stream>>>(inp, label, fn_f32, fn_bf16, counts);
    prep_wn<<<NC / 4, 256, 0, stream>>>(wt, wn_bf16);
    main_gemm<<<dim3(8, GRIDY), 256, 0, stream>>>(fn_bf16, wn_bf16, label, sumexp, pos);
    loss_k<<<1, 256, 0, stream>>>(sumexp, pos, out);
    wout_k<<<NC * D / 256, 256, 0, stream>>>(wt, counts, out + 1);
    addmean_k<<<BS, D, 0, stream>>>(fn_f32, label, counts, out + 1);
}

// Round 2
// 162.661 us; speedup vs baseline: 1.6516x; 1.6516x over previous
//
#include <hip/hip_runtime.h>

#define BS 1024
#define D 128
#define NC 100000
#define NCP 100096           /* padded to 782*128 */
#define NTILES 782
#define S_SCALE 30.0f
#define MARGIN 0.35f
#define GRIDX 64             /* tile-phase blocks; 64*8 = 512 = 2 blocks/CU exactly */

typedef __attribute__((ext_vector_type(8))) short bf16x8;
typedef __attribute__((ext_vector_type(4))) float f32x4;

__device__ __forceinline__ unsigned short f2bf(float f) {
    union { float f; unsigned u; } x; x.f = f;
    unsigned u = x.u;
    u += 0x7FFFu + ((u >> 16) & 1u);   // round-to-nearest-even
    return (unsigned short)(u >> 16);
}

// Async global->LDS, 16B per lane. Dest is wave-uniform base; HW adds lane*16.
__device__ __forceinline__ void gld_lds16(const void* g, void* l) {
    auto gp = (const __attribute__((address_space(1))) unsigned int*)(g);
    auto lp = (__attribute__((address_space(3))) unsigned int*)(l);
    __builtin_amdgcn_global_load_lds(gp, lp, 16, 0, 0);
}

// One wave per input row: l2-normalize, emit f32 + swizzled bf16, count labels,
// and compute pos[row] = S * dot(fn, l2norm(weight[label])) exactly in f32.
__global__ void prep_fn(const float* __restrict__ inp, const int* __restrict__ label,
                        const float* __restrict__ wt,
                        float* __restrict__ fn_f32, unsigned short* __restrict__ fn_sw,
                        float* __restrict__ counts, float* __restrict__ pos) {
    int row = blockIdx.x;
    int lane = threadIdx.x;  // blockDim = 64
    float2 v = *(const float2*)(inp + row * D + lane * 2);
    float s = v.x * v.x + v.y * v.y;
    #pragma unroll
    for (int m = 1; m < 64; m <<= 1) s += __shfl_xor(s, m);
    float inv = 1.0f / fmaxf(sqrtf(s), 1e-12f);
    float a = v.x * inv, b = v.y * inv;
    *(float2*)(fn_f32 + row * D + lane * 2) = make_float2(a, b);
    // swizzled bf16: granule g=lane>>2 -> slot g^(row&15); 4B per lane within granule
    unsigned pack = (unsigned)f2bf(a) | ((unsigned)f2bf(b) << 16);
    ((unsigned*)fn_sw)[row * 64 + (((lane >> 2) ^ (row & 15)) << 2) + (lane & 3)] = pack;

    // pos: exact f32 cosine with the label's normalized weight row
    int c = label[row];
    float2 wv = *(const float2*)(wt + c * D + lane * 2);
    float sw_ = wv.x * wv.x + wv.y * wv.y;
    float dt  = wv.x * a + wv.y * b;
    #pragma unroll
    for (int m = 1; m < 64; m <<= 1) { sw_ += __shfl_xor(sw_, m); dt += __shfl_xor(dt, m); }
    if (lane == 0) {
        float invw = 1.0f / fmaxf(sqrtf(sw_), 1e-12f);
        pos[row] = S_SCALE * dt * invw;
        atomicAdd(counts + c, 1.0f);
    }
}

// 4 waves/block, one weight row per wave: l2-normalize -> swizzled bf16 global.
// Fused: write weight output (copy if class absent, 0 if present). Pad rows -> 0.
__global__ void prep_wn(const float* __restrict__ wt, const float* __restrict__ counts,
                        unsigned short* __restrict__ wn_sw, float* __restrict__ outw) {
    int wv = threadIdx.x >> 6, lane = threadIdx.x & 63;
    int row = blockIdx.x * 4 + wv;      // grid 25024 -> 100096 incl. pad
    int t = row >> 7, c = row & 127;
    unsigned* dst = (unsigned*)wn_sw + t * 8192 + c * 64 +
                    (((lane >> 2) ^ (c & 15)) << 2) + (lane & 3);
    if (row < NC) {
        float2 v = *(const float2*)(wt + row * D + lane * 2);
        float s = v.x * v.x + v.y * v.y;
        #pragma unroll
        for (int m = 1; m < 64; m <<= 1) s += __shfl_xor(s, m);
        float inv = 1.0f / fmaxf(sqrtf(s), 1e-12f);
        *dst = (unsigned)f2bf(v.x * inv) | ((unsigned)f2bf(v.y * inv) << 16);
        float cnt = counts[row];
        float2 o = (cnt > 0.0f) ? make_float2(0.0f, 0.0f) : v;
        *(float2*)(outw + row * D + lane * 2) = o;
    } else {
        *dst = 0u;   // pad classes: zero vector -> logit 0 -> e^-30, negligible
    }
}

// Main fused GEMM + exp-accumulate. Block = 256 thr (4 waves, 2x2 over 128x128 tile).
// A and B staged via global_load_lds (16B) from pre-swizzled global buffers.
// No label handling in the hot loop: sum over ALL columns; label term subtracted later.
__global__ __launch_bounds__(256, 2) void main_gemm(
    const unsigned short* __restrict__ fnsw, const unsigned short* __restrict__ wnsw,
    float* __restrict__ sumexp) {
    __shared__ __align__(16) short As[128 * 128];  // 32 KB
    __shared__ __align__(16) short Bs[128 * 128];  // 32 KB
    int tid = threadIdx.x;
    int lane = tid & 63, w = tid >> 6;
    int quad = lane >> 4, l15 = lane & 15;
    int m0 = (w >> 1) * 64, n0 = (w & 1) * 64;
    int rowbase = blockIdx.y * 128;   // 8 row tiles cover 1024 rows

    // Stage A once: wave w copies bytes [w*8192, w*8192+8192) linearly.
    {
        const char* gA = (const char*)fnsw + rowbase * 256 + w * 8192 + lane * 16;
        char* lA = (char*)As + w * 8192;
        #pragma unroll
        for (int j = 0; j < 8; j++) gld_lds16(gA + j * 1024, lA + j * 1024);
    }

    float sums[16];
    #pragma unroll
    for (int i = 0; i < 16; i++) sums[i] = 0.0f;

    for (int tile = blockIdx.x; tile < NTILES; tile += GRIDX) {
        const char* gB = (const char*)wnsw + tile * 32768 + w * 8192 + lane * 16;
        char* lB = (char*)Bs + w * 8192;
        __syncthreads();   // prior tile's Bs reads complete before overwrite
        #pragma unroll
        for (int j = 0; j < 8; j++) gld_lds16(gB + j * 1024, lB + j * 1024);
        __syncthreads();   // staging drained (compiler emits vmcnt(0) before barrier)

        f32x4 acc[4][4];
        #pragma unroll
        for (int mt = 0; mt < 4; mt++)
            #pragma unroll
            for (int nt = 0; nt < 4; nt++)
                acc[mt][nt] = (f32x4){0.0f, 0.0f, 0.0f, 0.0f};

        #pragma unroll
        for (int ks = 0; ks < 4; ks++) {
            int kb = ks * 4 + quad;
            bf16x8 af[4], bf[4];
            #pragma unroll
            for (int mt = 0; mt < 4; mt++) {
                int row = m0 + mt * 16 + l15;          // row&15 == l15
                af[mt] = *(const bf16x8*)(As + (row * 16 + (kb ^ l15)) * 8);
            }
            #pragma unroll
            for (int nt = 0; nt < 4; nt++) {
                int row = n0 + nt * 16 + l15;
                bf[nt] = *(const bf16x8*)(Bs + (row * 16 + (kb ^ l15)) * 8);
            }
            #pragma unroll
            for (int mt = 0; mt < 4; mt++)
                #pragma unroll
                for (int nt = 0; nt < 4; nt++)
                    acc[mt][nt] = __builtin_amdgcn_mfma_f32_16x16x32_bf16(
                        af[mt], bf[nt], acc[mt][nt], 0, 0, 0);
        }

        // Epilogue: unconditional exp-accumulate (fma + exp + add per value).
        #pragma unroll
        for (int nt = 0; nt < 4; nt++)
            #pragma unroll
            for (int mt = 0; mt < 4; mt++)
                #pragma unroll
                for (int r = 0; r < 4; r++)
                    sums[mt * 4 + r] += __expf(fmaf(acc[mt][nt][r], S_SCALE, -30.0f));
    }

    // Reduce partials across the 16 lanes of each quad, one atomic per row per block.
    #pragma unroll
    for (int mt = 0; mt < 4; mt++) {
        #pragma unroll
        for (int r = 0; r < 4; r++) {
            float s = sums[mt * 4 + r];
            s += __shfl_xor(s, 1);
            s += __shfl_xor(s, 2);
            s += __shfl_xor(s, 4);
            s += __shfl_xor(s, 8);
            if (l15 == 0)
                atomicAdd(sumexp + rowbase + m0 + mt * 16 + quad * 4 + r, s);
        }
    }
}

// loss = mean softplus(M + 30 + log(sum_all - exp(pos-30)) - pos)
__global__ void loss_k(const float* __restrict__ sumexp, const float* __restrict__ pos,
                       float* __restrict__ out) {
    __shared__ float red[256];
    int t = threadIdx.x;
    float acc = 0.0f;
    #pragma unroll
    for (int i = 0; i < 4; i++) {
        int r = t + i * 256;
        float p = pos[r];
        float sneg = fmaxf(sumexp[r] - __expf(p - 30.0f), 1e-38f);
        float lse = 30.0f + logf(sneg);
        float z = MARGIN + lse - p;
        acc += fmaxf(z, 0.0f) + log1pf(__expf(-fabsf(z)));
    }
    red[t] = acc;
    __syncthreads();
    for (int s = 128; s > 0; s >>= 1) {
        if (t < s) red[t] += red[t + s];
        __syncthreads();
    }
    if (t == 0) out[0] = red[0] * (1.0f / 1024.0f);
}

__global__ void addmean_k(const float* __restrict__ fn_f32, const int* __restrict__ label,
                          const float* __restrict__ counts, float* __restrict__ outw) {
    int b = blockIdx.x, t = threadIdx.x;  // 1024 x 128
    int c = label[b];
    float cnt = counts[c];
    atomicAdd(outw + c * D + t, fn_f32[b * D + t] / cnt);
}

extern "C" void kernel_launch(void* const* d_in, const int* in_sizes, int n_in,
                              void* d_out, int out_size, void* d_ws, size_t ws_size,
                              hipStream_t stream) {
    (void)in_sizes; (void)n_in; (void)out_size; (void)ws_size;
    const float* inp   = (const float*)d_in[0];
    const int*   label = (const int*)d_in[1];
    const float* wt    = (const float*)d_in[2];
    float* out = (float*)d_out;

    char* w = (char*)d_ws;
    float*          fn_f32 = (float*)(w);                     // 524288 B
    unsigned short* fn_sw  = (unsigned short*)(w + 524288);   // 262144 B
    unsigned short* wn_sw  = (unsigned short*)(w + 786432);   // 25624576 B
    float*          sumexp = (float*)(w + 26411008);          // 4096 B
    float*          counts = (float*)(w + 26415104);          // 400000 B
    float*          pos    = (float*)(w + 26815104);          // 4096 B

    // zero sumexp + counts (contiguous)
    hipMemsetAsync(w + 26411008, 0, 404096, stream);

    prep_fn<<<BS, 64, 0, stream>>>(inp, label, wt, fn_f32, fn_sw, counts, pos);
    prep_wn<<<NCP / 4, 256, 0, stream>>>(wt, counts, wn_sw, out + 1);
    main_gemm<<<dim3(GRIDX, 8), 256, 0, stream>>>(fn_sw, wn_sw, sumexp);
    addmean_k<<<BS, D, 0, stream>>>(fn_f32, label, counts, out + 1);
    loss_k<<<1, 256, 0, stream>>>(sumexp, pos, out);
}